// Round 8
// baseline (1101.376 us; speedup 1.0000x reference)
//
#include <hip/hip_runtime.h>
#include <math.h>

#define B_  4
#define T_  1024
#define C_  1024
#define H_  16
#define HS_ 64
#define K2E 0.1803368801f   // 0.125 * log2(e)
#define LOG2E 1.44269504f

typedef _Float16 f16;
typedef _Float16 f16x8 __attribute__((ext_vector_type(8)));
typedef float f32x4 __attribute__((ext_vector_type(4)));

#define MFMA16(a,b,c) __builtin_amdgcn_mfma_f32_16x16x32_f16(a,b,c,0,0,0)
#define EXP2(x) __builtin_amdgcn_exp2f(x)
#define RCP(x)  __builtin_amdgcn_rcpf(x)

__device__ __forceinline__ float qsum_(float v){
    v += __shfl_xor(v,1,64); v += __shfl_xor(v,2,64);
    v += __shfl_xor(v,4,64); v += __shfl_xor(v,8,64);
    return v;
}
__device__ __forceinline__ float sigmoidf_(float x){ return 1.0f/(1.0f + __expf(-x)); }
__device__ __forceinline__ float softplusf_(float x){ return fmaxf(x, 0.0f) + log1pf(__expf(-fabsf(x))); }

// ---------------------------------------------------------------------------
// prep: region 0 = x fp32->f16 (2048 blocks); 1 = W_attn^T f16 (3072);
//       2 = W_proj^T f16 (1024); 3 = zero colp+racc (68). Total 6212 blocks.
// ---------------------------------------------------------------------------
__global__ __launch_bounds__(256) void prep_k(
    const float* __restrict__ x, const float* __restrict__ Wa,
    const float* __restrict__ Wp,
    f16* __restrict__ x_h, f16* __restrict__ WaT, f16* __restrict__ WpT,
    float* __restrict__ zbase)
{
    __shared__ float tl[32][33];
    const int bid = blockIdx.x, tid = threadIdx.x;
    if (bid < 2048){
        int i = bid*256 + tid;
        const float4* p = (const float4*)x + (size_t)i*2;
        float4 a = p[0], b = p[1];
        f16x8 o;
        o[0]=(f16)a.x; o[1]=(f16)a.y; o[2]=(f16)a.z; o[3]=(f16)a.w;
        o[4]=(f16)b.x; o[5]=(f16)b.y; o[6]=(f16)b.z; o[7]=(f16)b.w;
        *((f16x8*)x_h + i) = o;
    } else if (bid < 5120){
        int t = bid - 2048;
        int n0 = (t % 96)*32, k0 = (t / 96)*32;
        const int c = tid & 31, r4 = tid >> 5;
        #pragma unroll
        for (int i=0;i<4;i++){ int r = r4*4+i; tl[r][c] = Wa[(size_t)(k0+r)*3072 + n0 + c]; }
        __syncthreads();
        #pragma unroll
        for (int i=0;i<4;i++){ int r = r4*4+i; WaT[(size_t)(n0+r)*1024 + k0 + c] = (f16)tl[c][r]; }
    } else if (bid < 6144){
        int t = bid - 5120;
        int n0 = (t & 31)*32, k0 = (t >> 5)*32;
        const int c = tid & 31, r4 = tid >> 5;
        #pragma unroll
        for (int i=0;i<4;i++){ int r = r4*4+i; tl[r][c] = Wp[(size_t)(k0+r)*1024 + n0 + c]; }
        __syncthreads();
        #pragma unroll
        for (int i=0;i<4;i++){ int r = r4*4+i; WpT[(size_t)(n0+r)*1024 + k0 + c] = (f16)tl[c][r]; }
    } else {
        int idx = (bid - 6144)*256 + tid;   // float4 index; 17408 total (colp+racc)
        float4 z; z.x=0.f; z.y=0.f; z.z=0.f; z.w=0.f;
        ((float4*)zbase)[idx] = z;
    }
}

// ---------------------------------------------------------------------------
// GEMM qkv: 128x128x32, double-buffered LDS (1 barrier/iter), 2-set register
// prefetch. Epilogue: C-tile -> LDS -> dense f16x8 stores.
// ---------------------------------------------------------------------------
#define CT_STRIDE 132
__global__ __launch_bounds__(256) void gemm_qkv_k(
    const f16* __restrict__ A, const f16* __restrict__ Bt,
    const float* __restrict__ bias,
    f16* __restrict__ Qh, f16* __restrict__ Kh, f16* __restrict__ Vt)
{
    __shared__ __align__(16) f16 smem[16896];   // bufs: [0,8192) + [8192,16384); Ct aliases
    const int tid = threadIdx.x;
    const int lane = tid & 63, wave = tid >> 6;
    const int lx = lane & 15, quad = lane >> 4;
    const int wm = wave & 1, wn = wave >> 1;
    const int m0 = blockIdx.y*128, n0 = blockIdx.x*128;
    const f16* Ap = A  + (size_t)m0*1024;
    const f16* Bp = Bt + (size_t)n0*1024;
    f32x4 acc[4][4];
    #pragma unroll
    for (int i=0;i<4;i++){
        #pragma unroll
        for (int j=0;j<4;j++){ acc[i][j][0]=0.f;acc[i][j][1]=0.f;acc[i][j][2]=0.f;acc[i][j][3]=0.f; }
    }
    f16x8 ra[2][2], rb[2][2];
    #pragma unroll
    for (int i=0;i<2;i++){
        int c = i*4 + wave;
        ra[0][i] = *(const f16x8*)(Ap + (size_t)(c*16+lx)*1024 + quad*8);
        rb[0][i] = *(const f16x8*)(Bp + (size_t)(c*16+lx)*1024 + quad*8);
    }
    #pragma unroll
    for (int i=0;i<2;i++){
        int c = i*4 + wave;
        *(f16x8*)&smem[c*512 + quad*128 + lx*8]        = ra[0][i];
        *(f16x8*)&smem[4096 + c*512 + quad*128 + lx*8] = rb[0][i];
    }
    #pragma unroll
    for (int i=0;i<2;i++){
        int c = i*4 + wave;
        ra[1][i] = *(const f16x8*)(Ap + (size_t)(c*16+lx)*1024 + 32 + quad*8);
        rb[1][i] = *(const f16x8*)(Bp + (size_t)(c*16+lx)*1024 + 32 + quad*8);
    }
    __syncthreads();
    for (int it=0; it<32; it++){
        const int cur = (it&1)*8192, nxt = 8192 - cur, s = it&1;
        if (it < 30){
            #pragma unroll
            for (int i=0;i<2;i++){
                int c = i*4 + wave;
                ra[s][i] = *(const f16x8*)(Ap + (size_t)(c*16+lx)*1024 + (it+2)*32 + quad*8);
                rb[s][i] = *(const f16x8*)(Bp + (size_t)(c*16+lx)*1024 + (it+2)*32 + quad*8);
            }
        }
        if (it < 31){
            #pragma unroll
            for (int i=0;i<2;i++){
                int c = i*4 + wave;
                *(f16x8*)&smem[nxt + c*512 + quad*128 + lx*8]        = ra[s^1][i];
                *(f16x8*)&smem[nxt + 4096 + c*512 + quad*128 + lx*8] = rb[s^1][i];
            }
        }
        f16x8 af[4], bf[4];
        #pragma unroll
        for (int mt=0;mt<4;mt++) af[mt] = *(const f16x8*)&smem[cur + (wm*4+mt)*512 + quad*128 + lx*8];
        #pragma unroll
        for (int nt=0;nt<4;nt++) bf[nt] = *(const f16x8*)&smem[cur + 4096 + (wn*4+nt)*512 + quad*128 + lx*8];
        #pragma unroll
        for (int mt=0;mt<4;mt++){
            #pragma unroll
            for (int nt=0;nt<4;nt++)
                acc[mt][nt] = MFMA16(af[mt], bf[nt], acc[mt][nt]);
        }
        __syncthreads();
    }
    // epilogue: stage C-tile (f16, +bias) into LDS, then dense stores
    f16* Ct = smem;
    #pragma unroll
    for (int mt=0;mt<4;mt++){
        #pragma unroll
        for (int nt=0;nt<4;nt++){
            int n_loc = wn*64 + nt*16 + lx;
            float bv = bias[n0 + n_loc];
            #pragma unroll
            for (int r=0;r<4;r++){
                int m_loc = wm*64 + mt*16 + quad*4 + r;
                Ct[m_loc*CT_STRIDE + n_loc] = (f16)(acc[mt][nt][r] + bv);
            }
        }
    }
    __syncthreads();
    const int bb = m0 >> 10;
    if (n0 < 2048){
        for (int it=0; it<8; it++){
            int row = it*32 + wave*8 + (lane>>3);
            int ch  = lane & 7;
            int m_loc = row >> 1, half = row & 1;
            f16x8 v = *(const f16x8*)&Ct[m_loc*CT_STRIDE + half*64 + ch*8];
            int n = n0 + half*64;
            int which = n >> 10, cc = n & 1023, h = cc >> 6;
            int t = (m0 + m_loc) & 1023;
            f16* dst = (which==0) ? Qh : Kh;
            *(f16x8*)(dst + ((size_t)(bb*16+h)*1024 + t)*64 + ch*8) = v;
        }
    } else {
        for (int it=0; it<8; it++){
            int drow = it*16 + wave*4 + (lane>>4);
            int ch   = lane & 15;
            int cc = (n0 + drow) & 1023;
            int h = cc >> 6, d = cc & 63;
            f16 tmp[8];
            #pragma unroll
            for (int j=0;j<8;j++) tmp[j] = Ct[(ch*8+j)*CT_STRIDE + drow];
            int t = (m0 + ch*8) & 1023;
            *(f16x8*)(Vt + ((size_t)(bb*16+h)*64 + d)*1024 + t) = *(f16x8*)tmp;
        }
    }
}

// ---------------------------------------------------------------------------
// GEMM proj: 128x64x32, double-buffered LDS; block 512 = finish_refr.
// ---------------------------------------------------------------------------
__global__ __launch_bounds__(256) void gemm_proj_k(
    const f16* __restrict__ A, const f16* __restrict__ Bt,
    const float* __restrict__ bias, float* __restrict__ out,
    const float* __restrict__ racc)
{
    if (blockIdx.x == 512){
        float* oref = out + (size_t)B_*T_*C_;
        #pragma unroll
        for (int j=0;j<16;j++){
            int idx = j*256 + threadIdx.x;
            oref[idx] = racc[idx] * (1.0f/(H_*T_));
        }
        return;
    }
    __shared__ __align__(16) f16 smem[12288];  // bufs at 0 / 6144; B at +4096
    const int tid = threadIdx.x;
    const int lane = tid & 63, wave = tid >> 6;
    const int lx = lane & 15, quad = lane >> 4;
    const int wm = wave & 1, wn = wave >> 1;
    const int m0 = (blockIdx.x >> 4)*128, n0 = (blockIdx.x & 15)*64;
    const f16* Ap = A  + (size_t)m0*1024;
    const f16* Bp = Bt + (size_t)n0*1024;
    f32x4 acc[4][2];
    #pragma unroll
    for (int i=0;i<4;i++){
        #pragma unroll
        for (int j=0;j<2;j++){ acc[i][j][0]=0.f;acc[i][j][1]=0.f;acc[i][j][2]=0.f;acc[i][j][3]=0.f; }
    }
    f16x8 ra[2][2], rb[2];
    #pragma unroll
    for (int i=0;i<2;i++)
        ra[0][i] = *(const f16x8*)(Ap + (size_t)((i*4+wave)*16+lx)*1024 + quad*8);
    rb[0] = *(const f16x8*)(Bp + (size_t)(wave*16+lx)*1024 + quad*8);
    #pragma unroll
    for (int i=0;i<2;i++)
        *(f16x8*)&smem[(i*4+wave)*512 + quad*128 + lx*8] = ra[0][i];
    *(f16x8*)&smem[4096 + wave*512 + quad*128 + lx*8] = rb[0];
    #pragma unroll
    for (int i=0;i<2;i++)
        ra[1][i] = *(const f16x8*)(Ap + (size_t)((i*4+wave)*16+lx)*1024 + 32 + quad*8);
    rb[1] = *(const f16x8*)(Bp + (size_t)(wave*16+lx)*1024 + 32 + quad*8);
    __syncthreads();
    for (int it=0; it<32; it++){
        const int cur = (it&1)*6144, nxt = 6144 - cur, s = it&1;
        if (it < 30){
            #pragma unroll
            for (int i=0;i<2;i++)
                ra[s][i] = *(const f16x8*)(Ap + (size_t)((i*4+wave)*16+lx)*1024 + (it+2)*32 + quad*8);
            rb[s] = *(const f16x8*)(Bp + (size_t)(wave*16+lx)*1024 + (it+2)*32 + quad*8);
        }
        if (it < 31){
            #pragma unroll
            for (int i=0;i<2;i++)
                *(f16x8*)&smem[nxt + (i*4+wave)*512 + quad*128 + lx*8] = ra[s^1][i];
            *(f16x8*)&smem[nxt + 4096 + wave*512 + quad*128 + lx*8] = rb[s^1];
        }
        f16x8 af[4], bf[2];
        #pragma unroll
        for (int mt=0;mt<4;mt++) af[mt] = *(const f16x8*)&smem[cur + (wm*4+mt)*512 + quad*128 + lx*8];
        #pragma unroll
        for (int nt=0;nt<2;nt++) bf[nt] = *(const f16x8*)&smem[cur + 4096 + (wn*2+nt)*512 + quad*128 + lx*8];
        #pragma unroll
        for (int mt=0;mt<4;mt++){
            #pragma unroll
            for (int nt=0;nt<2;nt++)
                acc[mt][nt] = MFMA16(af[mt], bf[nt], acc[mt][nt]);
        }
        __syncthreads();
    }
    #pragma unroll
    for (int mt=0;mt<4;mt++){
        #pragma unroll
        for (int nt=0;nt<2;nt++){
            int n = n0 + wn*32 + nt*16 + lx;
            float bv = bias[n];
            #pragma unroll
            for (int r=0;r<4;r++){
                int m = m0 + wm*64 + mt*16 + quad*4 + r;
                out[(size_t)m*1024 + n] = acc[mt][nt][r] + bv;
            }
        }
    }
}

// ---------------------------------------------------------------------------
// attn_stats: double-buffered K tiles, 1 barrier/iter; cacc LDS accumulator.
// ---------------------------------------------------------------------------
__global__ __launch_bounds__(256) void attn_stats_k(
    const f16* __restrict__ Qh, const f16* __restrict__ Kh,
    float* __restrict__ rowl, float* __restrict__ colp)
{
    __shared__ __align__(16) f16 Kl[8192];   // 2 bufs of 4096
    __shared__ float cacc[1024];
    const int tid = threadIdx.x;
    const int lane = tid & 63, wave = tid >> 6;
    const int lx = lane & 15, quad = lane >> 4;
    const int g  = 15 - (blockIdx.x >> 6);
    const int bh = blockIdx.x & 63;
    const int qpos = wave*16 + quad*4;
    const size_t kbase = (size_t)bh*65536;

    for (int i=tid; i<1024; i+=256) cacc[i] = 0.f;

    const size_t qoff = ((size_t)bh*1024 + g*64 + wave*16 + lx)*64;
    f16x8 aq0 = *(const f16x8*)(Qh + qoff + quad*8);
    f16x8 aq1 = *(const f16x8*)(Qh + qoff + 32 + quad*8);

    f16x8 rk[2][2];
    // ---- sweep 1 ----
    #pragma unroll
    for (int i=0;i<2;i++){ int u=i*4+wave, cc=u&3, kh=u>>2;
        rk[0][i] = *(const f16x8*)(Kh + kbase + (size_t)(cc*16+lx)*64 + kh*32 + quad*8); }
    #pragma unroll
    for (int i=0;i<2;i++){ int u=i*4+wave, cc=u&3, kh=u>>2;
        *(f16x8*)&Kl[cc*1024 + kh*512 + quad*128 + lx*8] = rk[0][i]; }
    if (g >= 1){
        #pragma unroll
        for (int i=0;i<2;i++){ int u=i*4+wave, cc=u&3, kh=u>>2;
            rk[1][i] = *(const f16x8*)(Kh + kbase + (size_t)(64 + cc*16+lx)*64 + kh*32 + quad*8); }
    }
    __syncthreads();
    float ls[4] = {0.f,0.f,0.f,0.f};
    for (int kt=0; kt<=g; kt++){
        const int cur = (kt&1)*4096, nxt = 4096 - cur, s = kt&1;
        if (kt+2 <= g){
            #pragma unroll
            for (int i=0;i<2;i++){ int u=i*4+wave, cc=u&3, kh=u>>2;
                rk[s][i] = *(const f16x8*)(Kh + kbase + (size_t)((kt+2)*64 + cc*16+lx)*64 + kh*32 + quad*8); }
        }
        if (kt+1 <= g){
            #pragma unroll
            for (int i=0;i<2;i++){ int u=i*4+wave, cc=u&3, kh=u>>2;
                *(f16x8*)&Kl[nxt + cc*1024 + kh*512 + quad*128 + lx*8] = rk[s^1][i]; }
        }
        const bool diag = (kt == g);
        #pragma unroll
        for (int nt=0;nt<4;nt++){
            f32x4 sc = {0.f,0.f,0.f,0.f};
            f16x8 b0 = *(const f16x8*)&Kl[cur + nt*1024 + quad*128 + lx*8];
            f16x8 b1 = *(const f16x8*)&Kl[cur + nt*1024 + 512 + quad*128 + lx*8];
            sc = MFMA16(aq0, b0, sc);
            sc = MFMA16(aq1, b1, sc);
            #pragma unroll
            for (int r=0;r<4;r++){
                float sv = sc[r];
                if (diag && (nt*16+lx) > (qpos + r)) sv = -1e4f;
                ls[r] += EXP2(sv*K2E);
            }
        }
        __syncthreads();
    }
    float invl[4];
    #pragma unroll
    for (int r=0;r<4;r++){
        float l = qsum_(ls[r]);
        if (lx == 0) rowl[(size_t)bh*1024 + g*64 + qpos + r] = l;
        invl[r] = RCP(l);
    }
    // ---- sweep 2 ----
    #pragma unroll
    for (int i=0;i<2;i++){ int u=i*4+wave, cc=u&3, kh=u>>2;
        rk[0][i] = *(const f16x8*)(Kh + kbase + (size_t)(cc*16+lx)*64 + kh*32 + quad*8); }
    #pragma unroll
    for (int i=0;i<2;i++){ int u=i*4+wave, cc=u&3, kh=u>>2;
        *(f16x8*)&Kl[cc*1024 + kh*512 + quad*128 + lx*8] = rk[0][i]; }
    if (g >= 1){
        #pragma unroll
        for (int i=0;i<2;i++){ int u=i*4+wave, cc=u&3, kh=u>>2;
            rk[1][i] = *(const f16x8*)(Kh + kbase + (size_t)(64 + cc*16+lx)*64 + kh*32 + quad*8); }
    }
    __syncthreads();
    for (int kt=0; kt<=g; kt++){
        const int cur = (kt&1)*4096, nxt = 4096 - cur, s = kt&1;
        if (kt+2 <= g){
            #pragma unroll
            for (int i=0;i<2;i++){ int u=i*4+wave, cc=u&3, kh=u>>2;
                rk[s][i] = *(const f16x8*)(Kh + kbase + (size_t)((kt+2)*64 + cc*16+lx)*64 + kh*32 + quad*8); }
        }
        if (kt+1 <= g){
            #pragma unroll
            for (int i=0;i<2;i++){ int u=i*4+wave, cc=u&3, kh=u>>2;
                *(f16x8*)&Kl[nxt + cc*1024 + kh*512 + quad*128 + lx*8] = rk[s^1][i]; }
        }
        const bool diag = (kt == g);
        #pragma unroll
        for (int nt=0;nt<4;nt++){
            f32x4 sc = {0.f,0.f,0.f,0.f};
            f16x8 b0 = *(const f16x8*)&Kl[cur + nt*1024 + quad*128 + lx*8];
            f16x8 b1 = *(const f16x8*)&Kl[cur + nt*1024 + 512 + quad*128 + lx*8];
            sc = MFMA16(aq0, b0, sc);
            sc = MFMA16(aq1, b1, sc);
            float csum = 0.f;
            #pragma unroll
            for (int r=0;r<4;r++){
                float sv = sc[r];
                if (diag && (nt*16+lx) > (qpos + r)) sv = -1e4f;
                csum += EXP2(sv*K2E) * invl[r];
            }
            csum += __shfl_xor(csum,16,64); csum += __shfl_xor(csum,32,64);
            if (quad == 0) atomicAdd(&cacc[kt*64 + nt*16 + lx], csum);
        }
        __syncthreads();
    }
    for (int i=tid; i<(g+1)*64; i+=256)
        atomicAdd(&colp[(size_t)bh*1024 + i], cacc[i]);
}

// ---------------------------------------------------------------------------
// attn_apply: double-buffered K+V tiles, 1 barrier/iter; eb precomputed with
// st2 folded; cacc LDS accumulator; dense Yh stores via Pl.
// ---------------------------------------------------------------------------
__global__ __launch_bounds__(256) void attn_apply_k(
    const f16* __restrict__ Qh, const f16* __restrict__ Kh, const f16* __restrict__ Vt,
    const float* __restrict__ rowl,
    const float* __restrict__ colp, const float* __restrict__ refr,
    const float* __restrict__ threshold, const float* __restrict__ leak,
    const float* __restrict__ steepness, const float* __restrict__ ref_strength,
    const float* __restrict__ cross_w,
    f16* __restrict__ Yh, float* __restrict__ racc)
{
    __shared__ __align__(16) f16 Kl[8192];
    __shared__ __align__(16) f16 Vl[8192];
    __shared__ __align__(16) f16 Pl[4][16*72];
    __shared__ float eb[1024];
    __shared__ float cacc[1024];
    const int tid = threadIdx.x;
    const int lane = tid & 63, wave = tid >> 6;
    const int lx = lane & 15, quad = lane >> 4;
    const int g  = 15 - (blockIdx.x >> 6);
    const int bh = blockIdx.x & 63;
    const int b  = bh >> 4, h = bh & 15;
    const int qpos = wave*16 + quad*4;
    const size_t kbase = (size_t)bh*65536;

    const float thr = fabsf(threshold[h])*0.1f;
    const float lk  = sigmoidf_(leak[h]);
    const float st2 = softplusf_(steepness[h]) * LOG2E;
    const float sprT= softplusf_(ref_strength[h]) * (1.0f/T_);
    const float cw  = sigmoidf_(cross_w[h]);
    const float Alk = 1.f - lk;

    {
        float4 cp = *(const float4*)(colp + (size_t)bh*1024 + tid*4);
        float4 rf = *(const float4*)(refr + (size_t)b*1024 + tid*4);
        eb[tid*4+0] = st2*(thr + sprT*cp.x + cw*rf.x);
        eb[tid*4+1] = st2*(thr + sprT*cp.y + cw*rf.y);
        eb[tid*4+2] = st2*(thr + sprT*cp.z + cw*rf.z);
        eb[tid*4+3] = st2*(thr + sprT*cp.w + cw*rf.w);
    }
    for (int i=tid; i<1024; i+=256) cacc[i] = 0.f;

    const size_t qoff = ((size_t)bh*1024 + g*64 + wave*16 + lx)*64;
    f16x8 aq0 = *(const f16x8*)(Qh + qoff + quad*8);
    f16x8 aq1 = *(const f16x8*)(Qh + qoff + 32 + quad*8);

    float invl[4];
    #pragma unroll
    for (int r=0;r<4;r++)
        invl[r] = RCP(rowl[(size_t)bh*1024 + g*64 + qpos + r]);

    f32x4 y[4];
    #pragma unroll
    for (int i=0;i<4;i++){ y[i][0]=0.f;y[i][1]=0.f;y[i][2]=0.f;y[i][3]=0.f; }
    float Dp[4] = {0.f,0.f,0.f,0.f};

    f16x8 rk[2][2], rv[2][2];
    // ---- sweep 1 preamble ----
    #pragma unroll
    for (int i=0;i<2;i++){ int u=i*4+wave, cc=u&3, kh=u>>2;
        rk[0][i] = *(const f16x8*)(Kh + kbase + (size_t)(cc*16+lx)*64 + kh*32 + quad*8);
        rv[0][i] = *(const f16x8*)(Vt + kbase + (size_t)(cc*16+lx)*1024 + kh*32 + quad*8); }
    #pragma unroll
    for (int i=0;i<2;i++){ int u=i*4+wave, cc=u&3, kh=u>>2;
        *(f16x8*)&Kl[cc*1024 + kh*512 + quad*128 + lx*8] = rk[0][i];
        *(f16x8*)&Vl[cc*1024 + kh*512 + quad*128 + lx*8] = rv[0][i]; }
    if (g >= 1){
        #pragma unroll
        for (int i=0;i<2;i++){ int u=i*4+wave, cc=u&3, kh=u>>2;
            rk[1][i] = *(const f16x8*)(Kh + kbase + (size_t)(64 + cc*16+lx)*64 + kh*32 + quad*8);
            rv[1][i] = *(const f16x8*)(Vt + kbase + (size_t)(cc*16+lx)*1024 + 64 + kh*32 + quad*8); }
    }
    __syncthreads();
    for (int kt=0; kt<=g; kt++){
        const int cur = (kt&1)*4096, nxt = 4096 - cur, s = kt&1;
        if (kt+2 <= g){
            #pragma unroll
            for (int i=0;i<2;i++){ int u=i*4+wave, cc=u&3, kh=u>>2;
                rk[s][i] = *(const f16x8*)(Kh + kbase + (size_t)((kt+2)*64 + cc*16+lx)*64 + kh*32 + quad*8);
                rv[s][i] = *(const f16x8*)(Vt + kbase + (size_t)(cc*16+lx)*1024 + (kt+2)*64 + kh*32 + quad*8); }
        }
        if (kt+1 <= g){
            #pragma unroll
            for (int i=0;i<2;i++){ int u=i*4+wave, cc=u&3, kh=u>>2;
                *(f16x8*)&Kl[nxt + cc*1024 + kh*512 + quad*128 + lx*8] = rk[s^1][i];
                *(f16x8*)&Vl[nxt + cc*1024 + kh*512 + quad*128 + lx*8] = rv[s^1][i]; }
        }
        const bool diag = (kt == g);
        #pragma unroll
        for (int nt=0;nt<4;nt++){
            f32x4 sc = {0.f,0.f,0.f,0.f};
            f16x8 b0 = *(const f16x8*)&Kl[cur + nt*1024 + quad*128 + lx*8];
            f16x8 b1 = *(const f16x8*)&Kl[cur + nt*1024 + 512 + quad*128 + lx*8];
            sc = MFMA16(aq0, b0, sc);
            sc = MFMA16(aq1, b1, sc);
            float ec = eb[kt*64 + nt*16 + lx];
            #pragma unroll
            for (int r=0;r<4;r++){
                float sv = sc[r];
                if (diag && (nt*16+lx) > (qpos + r)) sv = -1e4f;
                float p = EXP2(sv*K2E) * invl[r];
                float fire = RCP(1.f + EXP2(ec - st2*p));
                float pw = p * (lk + Alk*fire);
                Dp[r] += pw;
                Pl[wave][(quad*4+r)*72 + nt*16 + lx] = (f16)pw;
            }
        }
        // Pl wave-private: lgkmcnt ordering suffices
        f16x8 ap0 = *(const f16x8*)&Pl[wave][lx*72 + quad*8];
        f16x8 ap1 = *(const f16x8*)&Pl[wave][lx*72 + 32 + quad*8];
        #pragma unroll
        for (int dt=0;dt<4;dt++){
            f16x8 bv0 = *(const f16x8*)&Vl[cur + dt*1024 + quad*128 + lx*8];
            f16x8 bv1 = *(const f16x8*)&Vl[cur + dt*1024 + 512 + quad*128 + lx*8];
            y[dt] = MFMA16(ap0, bv0, y[dt]);
            y[dt] = MFMA16(ap1, bv1, y[dt]);
        }
        __syncthreads();
    }
    float invD[4];
    #pragma unroll
    for (int r=0;r<4;r++) invD[r] = RCP(qsum_(Dp[r]) + 1e-8f);
    #pragma unroll
    for (int dt=0;dt<4;dt++){
        #pragma unroll
        for (int r=0;r<4;r++)
            Pl[wave][(quad*4+r)*72 + dt*16 + lx] = (f16)(y[dt][r]*invD[r]);
    }
    #pragma unroll
    for (int it=0; it<2; it++){
        int q = it*8 + (lane>>3), ch = lane & 7;
        f16x8 v = *(const f16x8*)&Pl[wave][q*72 + ch*8];
        *(f16x8*)(Yh + (size_t)(b*1024 + g*64 + wave*16 + q)*1024 + h*64 + ch*8) = v;
    }

    // ---- sweep 2 ----
    #pragma unroll
    for (int i=0;i<2;i++){ int u=i*4+wave, cc=u&3, kh=u>>2;
        rk[0][i] = *(const f16x8*)(Kh + kbase + (size_t)(cc*16+lx)*64 + kh*32 + quad*8); }
    #pragma unroll
    for (int i=0;i<2;i++){ int u=i*4+wave, cc=u&3, kh=u>>2;
        *(f16x8*)&Kl[cc*1024 + kh*512 + quad*128 + lx*8] = rk[0][i]; }
    if (g >= 1){
        #pragma unroll
        for (int i=0;i<2;i++){ int u=i*4+wave, cc=u&3, kh=u>>2;
            rk[1][i] = *(const f16x8*)(Kh + kbase + (size_t)(64 + cc*16+lx)*64 + kh*32 + quad*8); }
    }
    __syncthreads();
    for (int kt=0; kt<=g; kt++){
        const int cur = (kt&1)*4096, nxt = 4096 - cur, s = kt&1;
        if (kt+2 <= g){
            #pragma unroll
            for (int i=0;i<2;i++){ int u=i*4+wave, cc=u&3, kh=u>>2;
                rk[s][i] = *(const f16x8*)(Kh + kbase + (size_t)((kt+2)*64 + cc*16+lx)*64 + kh*32 + quad*8); }
        }
        if (kt+1 <= g){
            #pragma unroll
            for (int i=0;i<2;i++){ int u=i*4+wave, cc=u&3, kh=u>>2;
                *(f16x8*)&Kl[nxt + cc*1024 + kh*512 + quad*128 + lx*8] = rk[s^1][i]; }
        }
        const bool diag = (kt == g);
        #pragma unroll
        for (int nt=0;nt<4;nt++){
            f32x4 sc = {0.f,0.f,0.f,0.f};
            f16x8 b0 = *(const f16x8*)&Kl[cur + nt*1024 + quad*128 + lx*8];
            f16x8 b1 = *(const f16x8*)&Kl[cur + nt*1024 + 512 + quad*128 + lx*8];
            sc = MFMA16(aq0, b0, sc);
            sc = MFMA16(aq1, b1, sc);
            float ec = eb[kt*64 + nt*16 + lx];
            float csum = 0.f;
            #pragma unroll
            for (int r=0;r<4;r++){
                float sv = sc[r];
                if (diag && (nt*16+lx) > (qpos + r)) sv = -1e4f;
                float p = EXP2(sv*K2E) * invl[r];
                float fire = RCP(1.f + EXP2(ec - st2*p));
                csum += p * (lk + Alk*fire) * invD[r];
            }
            csum += __shfl_xor(csum,16,64); csum += __shfl_xor(csum,32,64);
            if (quad == 0) atomicAdd(&cacc[kt*64 + nt*16 + lx], csum);
        }
        __syncthreads();
    }
    for (int i=tid; i<(g+1)*64; i+=256)
        atomicAdd(&racc[(size_t)b*1024 + i], cacc[i]);
}

// ---------------------------------------------------------------------------
extern "C" void kernel_launch(void* const* d_in, const int* in_sizes, int n_in,
                              void* d_out, int out_size, void* d_ws, size_t ws_size,
                              hipStream_t stream) {
    (void)in_sizes; (void)n_in; (void)out_size; (void)ws_size;
    const float* x           = (const float*)d_in[0];
    const float* refr        = (const float*)d_in[1];
    const float* W_attn      = (const float*)d_in[2];
    const float* b_attn      = (const float*)d_in[3];
    const float* W_proj      = (const float*)d_in[4];
    const float* b_proj      = (const float*)d_in[5];
    const float* threshold   = (const float*)d_in[6];
    const float* leak        = (const float*)d_in[7];
    const float* steepness   = (const float*)d_in[8];
    const float* ref_strength= (const float*)d_in[9];
    const float* cross_w     = (const float*)d_in[10];
    float* out = (float*)d_out;

    char* ws = (char*)d_ws;
    f16* x_h = (f16*)ws;                       ws += (size_t)4096*1024*2;
    f16* WaT = (f16*)ws;                       ws += (size_t)3072*1024*2;
    f16* WpT = (f16*)ws;                       ws += (size_t)1024*1024*2;
    f16* Qh  = (f16*)ws;                       ws += (size_t)64*1024*64*2;
    f16* Kh  = (f16*)ws;                       ws += (size_t)64*1024*64*2;
    f16* Vt  = (f16*)ws;                       ws += (size_t)64*64*1024*2;
    f16* Yh  = (f16*)ws;                       ws += (size_t)4096*1024*2;
    float* rowl = (float*)ws;                  ws += (size_t)65536*4;
    float* colp = (float*)ws;                  ws += (size_t)65536*4;
    float* racc = (float*)ws;                  ws += (size_t)4096*4;   // adjacent to colp!

    prep_k<<<dim3(6212), dim3(256), 0, stream>>>(x, W_attn, W_proj, x_h, WaT, WpT, colp);
    gemm_qkv_k<<<dim3(24,32), dim3(256), 0, stream>>>(x_h, WaT, b_attn, Qh, Kh, Vt);
    attn_stats_k<<<dim3(1024), dim3(256), 0, stream>>>(Qh, Kh, rowl, colp);
    attn_apply_k<<<dim3(1024), dim3(256), 0, stream>>>(
        Qh, Kh, Vt, rowl, colp, refr,
        threshold, leak, steepness, ref_strength, cross_w, Yh, racc);
    gemm_proj_k<<<dim3(513), dim3(256), 0, stream>>>(Yh, WpT, b_proj, out, racc);
}

// Round 9
// 284.757 us; speedup vs baseline: 3.8678x; 3.8678x over previous
//
#include <hip/hip_runtime.h>
#include <math.h>

#define B_  4
#define T_  1024
#define C_  1024
#define H_  16
#define HS_ 64
#define K2E 0.1803368801f   // 0.125 * log2(e)
#define LOG2E 1.44269504f

typedef _Float16 f16;
typedef _Float16 f16x8 __attribute__((ext_vector_type(8)));
typedef float f32x4 __attribute__((ext_vector_type(4)));

#define MFMA16(a,b,c) __builtin_amdgcn_mfma_f32_16x16x32_f16(a,b,c,0,0,0)
#define EXP2(x) __builtin_amdgcn_exp2f(x)
#define RCP(x)  __builtin_amdgcn_rcpf(x)

__device__ __forceinline__ float qsum_(float v){
    v += __shfl_xor(v,1,64); v += __shfl_xor(v,2,64);
    v += __shfl_xor(v,4,64); v += __shfl_xor(v,8,64);
    return v;
}
__device__ __forceinline__ float sigmoidf_(float x){ return 1.0f/(1.0f + __expf(-x)); }
__device__ __forceinline__ float softplusf_(float x){ return fmaxf(x, 0.0f) + log1pf(__expf(-fabsf(x))); }

// ---------------------------------------------------------------------------
// prep: 0..2047 x->f16; 2048..5119 W_attn^T; 5120..6143 W_proj^T; rest zero.
// ---------------------------------------------------------------------------
__global__ __launch_bounds__(256) void prep_k(
    const float* __restrict__ x, const float* __restrict__ Wa,
    const float* __restrict__ Wp,
    f16* __restrict__ x_h, f16* __restrict__ WaT, f16* __restrict__ WpT,
    float* __restrict__ zbase)
{
    __shared__ float tl[32][33];
    const int bid = blockIdx.x, tid = threadIdx.x;
    if (bid < 2048){
        int i = bid*256 + tid;
        const float4* p = (const float4*)x + (size_t)i*2;
        float4 a = p[0], b = p[1];
        f16x8 o;
        o[0]=(f16)a.x; o[1]=(f16)a.y; o[2]=(f16)a.z; o[3]=(f16)a.w;
        o[4]=(f16)b.x; o[5]=(f16)b.y; o[6]=(f16)b.z; o[7]=(f16)b.w;
        *((f16x8*)x_h + i) = o;
    } else if (bid < 5120){
        int t = bid - 2048;
        int n0 = (t % 96)*32, k0 = (t / 96)*32;
        const int c = tid & 31, r4 = tid >> 5;
        #pragma unroll
        for (int i=0;i<4;i++){ int r = r4*4+i; tl[r][c] = Wa[(size_t)(k0+r)*3072 + n0 + c]; }
        __syncthreads();
        #pragma unroll
        for (int i=0;i<4;i++){ int r = r4*4+i; WaT[(size_t)(n0+r)*1024 + k0 + c] = (f16)tl[c][r]; }
    } else if (bid < 6144){
        int t = bid - 5120;
        int n0 = (t & 31)*32, k0 = (t >> 5)*32;
        const int c = tid & 31, r4 = tid >> 5;
        #pragma unroll
        for (int i=0;i<4;i++){ int r = r4*4+i; tl[r][c] = Wp[(size_t)(k0+r)*1024 + n0 + c]; }
        __syncthreads();
        #pragma unroll
        for (int i=0;i<4;i++){ int r = r4*4+i; WpT[(size_t)(n0+r)*1024 + k0 + c] = (f16)tl[c][r]; }
    } else {
        int idx = (bid - 6144)*256 + tid;   // 17408 float4 = colp + racc
        float4 z; z.x=0.f; z.y=0.f; z.z=0.f; z.w=0.f;
        ((float4*)zbase)[idx] = z;
    }
}

// ---------------------------------------------------------------------------
// GEMM qkv: 128x128x32, manually-unrolled double-buffered LDS (1 barrier/iter),
// named even/odd register sets (NO dynamic register indexing).
// ---------------------------------------------------------------------------
#define CT_STRIDE 132
__global__ __launch_bounds__(256) void gemm_qkv_k(
    const f16* __restrict__ A, const f16* __restrict__ Bt,
    const float* __restrict__ bias,
    f16* __restrict__ Qh, f16* __restrict__ Kh, f16* __restrict__ Vt)
{
    __shared__ __align__(16) f16 smem[16896];  // bufA 0..8191, bufB 8192..16383; Ct aliases
    const int tid = threadIdx.x;
    const int lane = tid & 63, wave = tid >> 6;
    const int lx = lane & 15, quad = lane >> 4;
    const int wm = wave & 1, wn = wave >> 1;
    const int m0 = blockIdx.y*128, n0 = blockIdx.x*128;
    const f16* Ap = A  + (size_t)m0*1024;
    const f16* Bp = Bt + (size_t)n0*1024;
    f32x4 acc[4][4];
    #pragma unroll
    for (int i=0;i<4;i++){
        #pragma unroll
        for (int j=0;j<4;j++){ acc[i][j][0]=0.f;acc[i][j][1]=0.f;acc[i][j][2]=0.f;acc[i][j][3]=0.f; }
    }
#define GQ_LOAD(rA,rB,K0) { \
    for (int i=0;i<2;i++){ int c=i*4+wave; \
        rA[i] = *(const f16x8*)(Ap + (size_t)(c*16+lx)*1024 + (K0) + quad*8); \
        rB[i] = *(const f16x8*)(Bp + (size_t)(c*16+lx)*1024 + (K0) + quad*8); } }
#define GQ_STORE(rA,rB,BUF) { \
    for (int i=0;i<2;i++){ int c=i*4+wave; \
        *(f16x8*)&smem[(BUF) + c*512 + quad*128 + lx*8]        = rA[i]; \
        *(f16x8*)&smem[(BUF) + 4096 + c*512 + quad*128 + lx*8] = rB[i]; } }
#define GQ_COMP(BUF) { \
    f16x8 af[4], bf[4]; \
    for (int mt=0;mt<4;mt++) af[mt] = *(const f16x8*)&smem[(BUF) + (wm*4+mt)*512 + quad*128 + lx*8]; \
    for (int nt=0;nt<4;nt++) bf[nt] = *(const f16x8*)&smem[(BUF) + 4096 + (wn*4+nt)*512 + quad*128 + lx*8]; \
    for (int mt=0;mt<4;mt++) \
        for (int nt=0;nt<4;nt++) \
            acc[mt][nt] = MFMA16(af[mt], bf[nt], acc[mt][nt]); }

    f16x8 raE[2], rbE[2], raO[2], rbO[2];
    GQ_LOAD(raE, rbE, 0);
    GQ_STORE(raE, rbE, 0);
    GQ_LOAD(raO, rbO, 32);
    __syncthreads();
    #pragma unroll 1
    for (int it=0; it<32; it+=2){
        if (it+2 < 32) GQ_LOAD(raE, rbE, (it+2)*32);
        GQ_STORE(raO, rbO, 8192);
        GQ_COMP(0);
        __syncthreads();
        if (it+3 < 32) GQ_LOAD(raO, rbO, (it+3)*32);
        if (it+2 < 32) GQ_STORE(raE, rbE, 0);
        GQ_COMP(8192);
        __syncthreads();
    }
    // epilogue: C-tile -> LDS -> dense f16x8 stores
    f16* Ct = smem;
    #pragma unroll
    for (int mt=0;mt<4;mt++){
        #pragma unroll
        for (int nt=0;nt<4;nt++){
            int n_loc = wn*64 + nt*16 + lx;
            float bv = bias[n0 + n_loc];
            #pragma unroll
            for (int r=0;r<4;r++){
                int m_loc = wm*64 + mt*16 + quad*4 + r;
                Ct[m_loc*CT_STRIDE + n_loc] = (f16)(acc[mt][nt][r] + bv);
            }
        }
    }
    __syncthreads();
    const int bb = m0 >> 10;
    if (n0 < 2048){
        for (int it=0; it<8; it++){
            int row = it*32 + wave*8 + (lane>>3);
            int ch  = lane & 7;
            int m_loc = row >> 1, half = row & 1;
            f16x8 v = *(const f16x8*)&Ct[m_loc*CT_STRIDE + half*64 + ch*8];
            int n = n0 + half*64;
            int which = n >> 10, cc = n & 1023, h = cc >> 6;
            int t = (m0 + m_loc) & 1023;
            f16* dst = (which==0) ? Qh : Kh;
            *(f16x8*)(dst + ((size_t)(bb*16+h)*1024 + t)*64 + ch*8) = v;
        }
    } else {
        for (int it=0; it<8; it++){
            int drow = it*16 + wave*4 + (lane>>4);
            int ch   = lane & 15;
            int cc = (n0 + drow) & 1023;
            int h = cc >> 6, d = cc & 63;
            f16 tmp[8];
            #pragma unroll
            for (int j=0;j<8;j++) tmp[j] = Ct[(ch*8+j)*CT_STRIDE + drow];
            int t = (m0 + ch*8) & 1023;
            *(f16x8*)(Vt + ((size_t)(bb*16+h)*64 + d)*1024 + t) = *(f16x8*)tmp;
        }
    }
}

// ---------------------------------------------------------------------------
// GEMM proj: 128x64x32, manual dbuf; block 512 = finish_refr.
// ---------------------------------------------------------------------------
__global__ __launch_bounds__(256) void gemm_proj_k(
    const f16* __restrict__ A, const f16* __restrict__ Bt,
    const float* __restrict__ bias, float* __restrict__ out,
    const float* __restrict__ racc)
{
    if (blockIdx.x == 512){
        float* oref = out + (size_t)B_*T_*C_;
        #pragma unroll
        for (int j=0;j<16;j++){
            int idx = j*256 + threadIdx.x;
            oref[idx] = racc[idx] * (1.0f/(H_*T_));
        }
        return;
    }
    __shared__ __align__(16) f16 smem[12288];  // bufA 0..6143, bufB 6144..12287
    const int tid = threadIdx.x;
    const int lane = tid & 63, wave = tid >> 6;
    const int lx = lane & 15, quad = lane >> 4;
    const int wm = wave & 1, wn = wave >> 1;
    const int m0 = (blockIdx.x >> 4)*128, n0 = (blockIdx.x & 15)*64;
    const f16* Ap = A  + (size_t)m0*1024;
    const f16* Bp = Bt + (size_t)n0*1024;
    f32x4 acc[4][2];
    #pragma unroll
    for (int i=0;i<4;i++){
        #pragma unroll
        for (int j=0;j<2;j++){ acc[i][j][0]=0.f;acc[i][j][1]=0.f;acc[i][j][2]=0.f;acc[i][j][3]=0.f; }
    }
#define GP_LOAD(rA,rB,K0) { \
    for (int i=0;i<2;i++) \
        rA[i] = *(const f16x8*)(Ap + (size_t)((i*4+wave)*16+lx)*1024 + (K0) + quad*8); \
    rB = *(const f16x8*)(Bp + (size_t)(wave*16+lx)*1024 + (K0) + quad*8); }
#define GP_STORE(rA,rB,BUF) { \
    for (int i=0;i<2;i++) \
        *(f16x8*)&smem[(BUF) + (i*4+wave)*512 + quad*128 + lx*8] = rA[i]; \
    *(f16x8*)&smem[(BUF) + 4096 + wave*512 + quad*128 + lx*8] = rB; }
#define GP_COMP(BUF) { \
    f16x8 af[4], bf[2]; \
    for (int mt=0;mt<4;mt++) af[mt] = *(const f16x8*)&smem[(BUF) + (wm*4+mt)*512 + quad*128 + lx*8]; \
    for (int nt=0;nt<2;nt++) bf[nt] = *(const f16x8*)&smem[(BUF) + 4096 + (wn*2+nt)*512 + quad*128 + lx*8]; \
    for (int mt=0;mt<4;mt++) \
        for (int nt=0;nt<2;nt++) \
            acc[mt][nt] = MFMA16(af[mt], bf[nt], acc[mt][nt]); }

    f16x8 raE[2], raO[2], rbE, rbO;
    GP_LOAD(raE, rbE, 0);
    GP_STORE(raE, rbE, 0);
    GP_LOAD(raO, rbO, 32);
    __syncthreads();
    #pragma unroll 1
    for (int it=0; it<32; it+=2){
        if (it+2 < 32) GP_LOAD(raE, rbE, (it+2)*32);
        GP_STORE(raO, rbO, 6144);
        GP_COMP(0);
        __syncthreads();
        if (it+3 < 32) GP_LOAD(raO, rbO, (it+3)*32);
        if (it+2 < 32) GP_STORE(raE, rbE, 0);
        GP_COMP(6144);
        __syncthreads();
    }
    #pragma unroll
    for (int mt=0;mt<4;mt++){
        #pragma unroll
        for (int nt=0;nt<2;nt++){
            int n = n0 + wn*32 + nt*16 + lx;
            float bv = bias[n];
            #pragma unroll
            for (int r=0;r<4;r++){
                int m = m0 + wm*64 + mt*16 + quad*4 + r;
                out[(size_t)m*1024 + n] = acc[mt][nt][r] + bv;
            }
        }
    }
}

// ---------------------------------------------------------------------------
// attn_stats: manual even/odd dbuf (1 barrier/phase), cacc LDS accumulator.
// ---------------------------------------------------------------------------
__global__ __launch_bounds__(256) void attn_stats_k(
    const f16* __restrict__ Qh, const f16* __restrict__ Kh,
    float* __restrict__ rowl, float* __restrict__ colp)
{
    __shared__ __align__(16) f16 Kl[8192];   // bufA 0..4095, bufB 4096..8191
    __shared__ float cacc[1024];
    const int tid = threadIdx.x;
    const int lane = tid & 63, wave = tid >> 6;
    const int lx = lane & 15, quad = lane >> 4;
    const int g  = 15 - (blockIdx.x >> 6);
    const int bh = blockIdx.x & 63;
    const int qpos = wave*16 + quad*4;
    const size_t kbase = (size_t)bh*65536;

    for (int i=tid; i<1024; i+=256) cacc[i] = 0.f;

    const size_t qoff = ((size_t)bh*1024 + g*64 + wave*16 + lx)*64;
    f16x8 aq0 = *(const f16x8*)(Qh + qoff + quad*8);
    f16x8 aq1 = *(const f16x8*)(Qh + qoff + 32 + quad*8);

#define KLOAD(dst, KT) { \
    for (int i=0;i<2;i++){ int u=i*4+wave, cc=u&3, kh=u>>2; \
        dst[i] = *(const f16x8*)(Kh + kbase + (size_t)((KT)*64 + cc*16+lx)*64 + kh*32 + quad*8); } }
#define KSTORE(src, BUF) { \
    for (int i=0;i<2;i++){ int u=i*4+wave, cc=u&3, kh=u>>2; \
        *(f16x8*)&Kl[(BUF) + cc*1024 + kh*512 + quad*128 + lx*8] = src[i]; } }
#define STATS1_TILE(KT, BUF) { \
    const bool diag = ((KT) == g); \
    for (int nt=0;nt<4;nt++){ \
        f32x4 sc = {0.f,0.f,0.f,0.f}; \
        f16x8 b0 = *(const f16x8*)&Kl[(BUF) + nt*1024 + quad*128 + lx*8]; \
        f16x8 b1 = *(const f16x8*)&Kl[(BUF) + nt*1024 + 512 + quad*128 + lx*8]; \
        sc = MFMA16(aq0, b0, sc); \
        sc = MFMA16(aq1, b1, sc); \
        for (int r=0;r<4;r++){ \
            float sv = sc[r]; \
            if (diag && (nt*16+lx) > (qpos + r)) sv = -1e4f; \
            ls[r] += EXP2(sv*K2E); \
        } } }
#define STATS2_TILE(KT, BUF) { \
    const bool diag = ((KT) == g); \
    for (int nt=0;nt<4;nt++){ \
        f32x4 sc = {0.f,0.f,0.f,0.f}; \
        f16x8 b0 = *(const f16x8*)&Kl[(BUF) + nt*1024 + quad*128 + lx*8]; \
        f16x8 b1 = *(const f16x8*)&Kl[(BUF) + nt*1024 + 512 + quad*128 + lx*8]; \
        sc = MFMA16(aq0, b0, sc); \
        sc = MFMA16(aq1, b1, sc); \
        float csum = 0.f; \
        for (int r=0;r<4;r++){ \
            float sv = sc[r]; \
            if (diag && (nt*16+lx) > (qpos + r)) sv = -1e4f; \
            csum += EXP2(sv*K2E) * invl[r]; \
        } \
        csum += __shfl_xor(csum,16,64); csum += __shfl_xor(csum,32,64); \
        if (quad == 0) atomicAdd(&cacc[(KT)*64 + nt*16 + lx], csum); } }

    f16x8 rkE[2], rkO[2];
    float ls[4] = {0.f,0.f,0.f,0.f};
    // ---- sweep 1 ----
    KLOAD(rkE, 0);
    KSTORE(rkE, 0);
    if (g >= 1) KLOAD(rkO, 1);
    __syncthreads();
    #pragma unroll 1
    for (int kt=0; kt<=g; kt+=2){
        if (kt+2 <= g) KLOAD(rkE, kt+2);
        if (kt+1 <= g) KSTORE(rkO, 4096);
        STATS1_TILE(kt, 0);
        __syncthreads();
        if (kt+1 <= g){
            if (kt+3 <= g) KLOAD(rkO, kt+3);
            if (kt+2 <= g) KSTORE(rkE, 0);
            STATS1_TILE(kt+1, 4096);
            __syncthreads();
        }
    }
    float invl[4];
    #pragma unroll
    for (int r=0;r<4;r++){
        float l = qsum_(ls[r]);
        if (lx == 0) rowl[(size_t)bh*1024 + g*64 + qpos + r] = l;
        invl[r] = RCP(l);
    }
    // ---- sweep 2 ----
    KLOAD(rkE, 0);
    KSTORE(rkE, 0);
    if (g >= 1) KLOAD(rkO, 1);
    __syncthreads();
    #pragma unroll 1
    for (int kt=0; kt<=g; kt+=2){
        if (kt+2 <= g) KLOAD(rkE, kt+2);
        if (kt+1 <= g) KSTORE(rkO, 4096);
        STATS2_TILE(kt, 0);
        __syncthreads();
        if (kt+1 <= g){
            if (kt+3 <= g) KLOAD(rkO, kt+3);
            if (kt+2 <= g) KSTORE(rkE, 0);
            STATS2_TILE(kt+1, 4096);
            __syncthreads();
        }
    }
    for (int i=tid; i<(g+1)*64; i+=256)
        atomicAdd(&colp[(size_t)bh*1024 + i], cacc[i]);
}

// ---------------------------------------------------------------------------
// attn_apply: manual even/odd dbuf K+V, cacc accumulator, dense Yh stores.
// ---------------------------------------------------------------------------
__global__ __launch_bounds__(256) void attn_apply_k(
    const f16* __restrict__ Qh, const f16* __restrict__ Kh, const f16* __restrict__ Vt,
    const float* __restrict__ rowl,
    const float* __restrict__ colp, const float* __restrict__ refr,
    const float* __restrict__ threshold, const float* __restrict__ leak,
    const float* __restrict__ steepness, const float* __restrict__ ref_strength,
    const float* __restrict__ cross_w,
    f16* __restrict__ Yh, float* __restrict__ racc)
{
    __shared__ __align__(16) f16 Kl[8192];
    __shared__ __align__(16) f16 Vl[8192];
    __shared__ __align__(16) f16 Pl[4][16*72];
    __shared__ float eb[1024];
    __shared__ float cacc[1024];
    const int tid = threadIdx.x;
    const int lane = tid & 63, wave = tid >> 6;
    const int lx = lane & 15, quad = lane >> 4;
    const int g  = 15 - (blockIdx.x >> 6);
    const int bh = blockIdx.x & 63;
    const int b  = bh >> 4, h = bh & 15;
    const int qpos = wave*16 + quad*4;
    const size_t kbase = (size_t)bh*65536;

    const float thr = fabsf(threshold[h])*0.1f;
    const float lk  = sigmoidf_(leak[h]);
    const float st2 = softplusf_(steepness[h]) * LOG2E;
    const float sprT= softplusf_(ref_strength[h]) * (1.0f/T_);
    const float cw  = sigmoidf_(cross_w[h]);
    const float Alk = 1.f - lk;

    {
        float4 cp = *(const float4*)(colp + (size_t)bh*1024 + tid*4);
        float4 rf = *(const float4*)(refr + (size_t)b*1024 + tid*4);
        eb[tid*4+0] = st2*(thr + sprT*cp.x + cw*rf.x);
        eb[tid*4+1] = st2*(thr + sprT*cp.y + cw*rf.y);
        eb[tid*4+2] = st2*(thr + sprT*cp.z + cw*rf.z);
        eb[tid*4+3] = st2*(thr + sprT*cp.w + cw*rf.w);
    }
    for (int i=tid; i<1024; i+=256) cacc[i] = 0.f;

    const size_t qoff = ((size_t)bh*1024 + g*64 + wave*16 + lx)*64;
    f16x8 aq0 = *(const f16x8*)(Qh + qoff + quad*8);
    f16x8 aq1 = *(const f16x8*)(Qh + qoff + 32 + quad*8);

    float invl[4];
    #pragma unroll
    for (int r=0;r<4;r++)
        invl[r] = RCP(rowl[(size_t)bh*1024 + g*64 + qpos + r]);

    f32x4 y[4];
    #pragma unroll
    for (int i=0;i<4;i++){ y[i][0]=0.f;y[i][1]=0.f;y[i][2]=0.f;y[i][3]=0.f; }
    float Dp[4] = {0.f,0.f,0.f,0.f};

#define VLOAD(dst, KT) { \
    for (int i=0;i<2;i++){ int u=i*4+wave, cc=u&3, kh=u>>2; \
        dst[i] = *(const f16x8*)(Vt + kbase + (size_t)(cc*16+lx)*1024 + (KT)*64 + kh*32 + quad*8); } }
#define VSTORE(src, BUF) { \
    for (int i=0;i<2;i++){ int u=i*4+wave, cc=u&3, kh=u>>2; \
        *(f16x8*)&Vl[(BUF) + cc*1024 + kh*512 + quad*128 + lx*8] = src[i]; } }
#define APPLY1_TILE(KT, BUF) { \
    const bool diag = ((KT) == g); \
    for (int nt=0;nt<4;nt++){ \
        f32x4 sc = {0.f,0.f,0.f,0.f}; \
        f16x8 b0 = *(const f16x8*)&Kl[(BUF) + nt*1024 + quad*128 + lx*8]; \
        f16x8 b1 = *(const f16x8*)&Kl[(BUF) + nt*1024 + 512 + quad*128 + lx*8]; \
        sc = MFMA16(aq0, b0, sc); \
        sc = MFMA16(aq1, b1, sc); \
        float ec = eb[(KT)*64 + nt*16 + lx]; \
        for (int r=0;r<4;r++){ \
            float sv = sc[r]; \
            if (diag && (nt*16+lx) > (qpos + r)) sv = -1e4f; \
            float p = EXP2(sv*K2E) * invl[r]; \
            float fire = RCP(1.f + EXP2(ec - st2*p)); \
            float pw = p * (lk + Alk*fire); \
            Dp[r] += pw; \
            Pl[wave][(quad*4+r)*72 + nt*16 + lx] = (f16)pw; \
        } } \
    { f16x8 ap0 = *(const f16x8*)&Pl[wave][lx*72 + quad*8]; \
      f16x8 ap1 = *(const f16x8*)&Pl[wave][lx*72 + 32 + quad*8]; \
      for (int dt=0;dt<4;dt++){ \
        f16x8 bv0 = *(const f16x8*)&Vl[(BUF) + dt*1024 + quad*128 + lx*8]; \
        f16x8 bv1 = *(const f16x8*)&Vl[(BUF) + dt*1024 + 512 + quad*128 + lx*8]; \
        y[dt] = MFMA16(ap0, bv0, y[dt]); \
        y[dt] = MFMA16(ap1, bv1, y[dt]); } } }
#define APPLY2_TILE(KT, BUF) { \
    const bool diag = ((KT) == g); \
    for (int nt=0;nt<4;nt++){ \
        f32x4 sc = {0.f,0.f,0.f,0.f}; \
        f16x8 b0 = *(const f16x8*)&Kl[(BUF) + nt*1024 + quad*128 + lx*8]; \
        f16x8 b1 = *(const f16x8*)&Kl[(BUF) + nt*1024 + 512 + quad*128 + lx*8]; \
        sc = MFMA16(aq0, b0, sc); \
        sc = MFMA16(aq1, b1, sc); \
        float ec = eb[(KT)*64 + nt*16 + lx]; \
        float csum = 0.f; \
        for (int r=0;r<4;r++){ \
            float sv = sc[r]; \
            if (diag && (nt*16+lx) > (qpos + r)) sv = -1e4f; \
            float p = EXP2(sv*K2E) * invl[r]; \
            float fire = RCP(1.f + EXP2(ec - st2*p)); \
            csum += p * (lk + Alk*fire) * invD[r]; \
        } \
        csum += __shfl_xor(csum,16,64); csum += __shfl_xor(csum,32,64); \
        if (quad == 0) atomicAdd(&cacc[(KT)*64 + nt*16 + lx], csum); } }

    f16x8 rkE[2], rkO[2], rvE[2], rvO[2];
    // ---- sweep 1 ----
    KLOAD(rkE, 0); VLOAD(rvE, 0);
    KSTORE(rkE, 0); VSTORE(rvE, 0);
    if (g >= 1){ KLOAD(rkO, 1); VLOAD(rvO, 1); }
    __syncthreads();
    #pragma unroll 1
    for (int kt=0; kt<=g; kt+=2){
        if (kt+2 <= g){ KLOAD(rkE, kt+2); VLOAD(rvE, kt+2); }
        if (kt+1 <= g){ KSTORE(rkO, 4096); VSTORE(rvO, 4096); }
        APPLY1_TILE(kt, 0);
        __syncthreads();
        if (kt+1 <= g){
            if (kt+3 <= g){ KLOAD(rkO, kt+3); VLOAD(rvO, kt+3); }
            if (kt+2 <= g){ KSTORE(rkE, 0); VSTORE(rvE, 0); }
            APPLY1_TILE(kt+1, 4096);
            __syncthreads();
        }
    }
    float invD[4];
    #pragma unroll
    for (int r=0;r<4;r++) invD[r] = RCP(qsum_(Dp[r]) + 1e-8f);
    #pragma unroll
    for (int dt=0;dt<4;dt++){
        #pragma unroll
        for (int r=0;r<4;r++)
            Pl[wave][(quad*4+r)*72 + dt*16 + lx] = (f16)(y[dt][r]*invD[r]);
    }
    #pragma unroll
    for (int it=0; it<2; it++){
        int q = it*8 + (lane>>3), ch = lane & 7;
        f16x8 v = *(const f16x8*)&Pl[wave][q*72 + ch*8];
        *(f16x8*)(Yh + (size_t)(b*1024 + g*64 + wave*16 + q)*1024 + h*64 + ch*8) = v;
    }

    // ---- sweep 2 ----
    KLOAD(rkE, 0);
    KSTORE(rkE, 0);
    if (g >= 1) KLOAD(rkO, 1);
    __syncthreads();
    #pragma unroll 1
    for (int kt=0; kt<=g; kt+=2){
        if (kt+2 <= g) KLOAD(rkE, kt+2);
        if (kt+1 <= g) KSTORE(rkO, 4096);
        APPLY2_TILE(kt, 0);
        __syncthreads();
        if (kt+1 <= g){
            if (kt+3 <= g) KLOAD(rkO, kt+3);
            if (kt+2 <= g) KSTORE(rkE, 0);
            APPLY2_TILE(kt+1, 4096);
            __syncthreads();
        }
    }
    for (int i=tid; i<(g+1)*64; i+=256)
        atomicAdd(&racc[(size_t)b*1024 + i], cacc[i]);
}

// ---------------------------------------------------------------------------
extern "C" void kernel_launch(void* const* d_in, const int* in_sizes, int n_in,
                              void* d_out, int out_size, void* d_ws, size_t ws_size,
                              hipStream_t stream) {
    (void)in_sizes; (void)n_in; (void)out_size; (void)ws_size;
    const float* x           = (const float*)d_in[0];
    const float* refr        = (const float*)d_in[1];
    const float* W_attn      = (const float*)d_in[2];
    const float* b_attn      = (const float*)d_in[3];
    const float* W_proj      = (const float*)d_in[4];
    const float* b_proj      = (const float*)d_in[5];
    const float* threshold   = (const float*)d_in[6];
    const float* leak        = (const float*)d_in[7];
    const float* steepness   = (const float*)d_in[8];
    const float* ref_strength= (const float*)d_in[9];
    const float* cross_w     = (const float*)d_in[10];
    float* out = (float*)d_out;

    char* ws = (char*)d_ws;
    f16* x_h = (f16*)ws;                       ws += (size_t)4096*1024*2;
    f16* WaT = (f16*)ws;                       ws += (size_t)3072*1024*2;
    f16* WpT = (f16*)ws;                       ws += (size_t)1024*1024*2;
    f16* Qh  = (f16*)ws;                       ws += (size_t)64*1024*64*2;
    f16* Kh  = (f16*)ws;                       ws += (size_t)64*1024*64*2;
    f16* Vt  = (f16*)ws;                       ws += (size_t)64*64*1024*2;
    f16* Yh  = (f16*)ws;                       ws += (size_t)4096*1024*2;
    float* rowl = (float*)ws;                  ws += (size_t)65536*4;
    float* colp = (float*)ws;                  ws += (size_t)65536*4;
    float* racc = (float*)ws;                  ws += (size_t)4096*4;   // adjacent to colp!

    prep_k<<<dim3(6212), dim3(256), 0, stream>>>(x, W_attn, W_proj, x_h, WaT, WpT, colp);
    gemm_qkv_k<<<dim3(24,32), dim3(256), 0, stream>>>(x_h, WaT, b_attn, Qh, Kh, Vt);
    attn_stats_k<<<dim3(1024), dim3(256), 0, stream>>>(Qh, Kh, rowl, colp);
    attn_apply_k<<<dim3(1024), dim3(256), 0, stream>>>(
        Qh, Kh, Vt, rowl, colp, refr,
        threshold, leak, steepness, ref_strength, cross_w, Yh, racc);
    gemm_proj_k<<<dim3(513), dim3(256), 0, stream>>>(Yh, WpT, b_proj, out, racc);
}